// Round 6
// baseline (1342.409 us; speedup 1.0000x reference)
//
#include <hip/hip_runtime.h>
#include <cstdint>
#include <cstddef>

#define B_ 128
#define T_ 8192
#define F_ 10
#define F1_ 8
#define H1_ 8
#define H2_ 7
#define K_ 16
#define CHUNK 64
#define NC (T_/CHUNK)   // 128
#define RMASK 255       // 4-chunk ring (256 rows)

#define LOG2E 1.4426950408889634f

__device__ __forceinline__ float exp2_fast(float x){ float r; asm("v_exp_f32 %0, %1" : "=v"(r) : "v"(x)); return r; }
__device__ __forceinline__ float rcp_fast(float x){ float r; asm("v_rcp_f32 %0, %1" : "=v"(r) : "v"(x)); return r; }
template<int CTRL>
__device__ __forceinline__ float dppf(float x){
  return __int_as_float(__builtin_amdgcn_update_dpp(0, __float_as_int(x), CTRL, 0xF, 0xF, true));
}
// xor8 within each 16-lane row (row_ror:8) -- validated r2-r5
__device__ __forceinline__ float ror8(float x){ return dppf<0x128>(x); }
typedef int v2i_t __attribute__((ext_vector_type(2)));

// ---------------- Kernel 1: precompute LSTM1 gate inputs (pre-scaled) ------
__global__ __launch_bounds__(256) void k1_pre(const float* __restrict__ x,
    const float* __restrict__ conv_w, const float* __restrict__ conv_b,
    const float* __restrict__ w_ih1, const float* __restrict__ b_ih1,
    const float* __restrict__ b_hh1, float* __restrict__ g1pre)
{
  int g8 = threadIdx.x >> 3;
  int gl = threadIdx.x & 7;
  size_t idx = (size_t)blockIdx.x*32 + g8;    // (b*T + t)
  const float* xp = x + idx*F_;
  float xv[F_];
  #pragma unroll
  for (int f=0; f<F_; ++f) xv[f] = xp[f];
  float enc[F1_];
  #pragma unroll
  for (int o=0;o<F1_;++o){
    float a = conv_b[o];
    #pragma unroll
    for (int f=0;f<F_;++f) a += conv_w[o*F_+f]*xv[f];
    enc[o] = a > 0.f ? a : 0.01f*a;   // leaky_relu 0.01
  }
  float4 out;
  #pragma unroll
  for (int q=0;q<4;++q){
    int row = gl*4+q;
    float a = b_ih1[row]+b_hh1[row];
    #pragma unroll
    for (int o=0;o<F1_;++o) a += w_ih1[row*F1_+o]*enc[o];
    float s = (row>=16 && row<24) ? (-2.f*LOG2E) : (-LOG2E);  // fold act scale
    (&out.x)[q] = a*s;
  }
  ((float4*)(g1pre + idx*32))[gl] = out;
}

// ---------------- Kernel 2: wave-specialized stacked LSTMs -----------------
// Block = 2 waves. Wave A: LSTM1 + LSTM2's input projection (ff). Wave B:
// LSTM2 recurrence only, fed by the ff ring (1 ds_read_b32/step, stride-1).
// Ring rows are 64-wide; slot = lane; row r = ff[gate-row mapped by (u,c2,up)].
// Gate lane blocks (lane>>3): [i, g, i, g | f, o, f, o]; unit u = lane&7.
// After y: pr=permlane32_swap(y,y): pr.x=[i,g]-pattern all lanes, pr.y=[f,o].
//   IG = pr.x * ror8(pr.x) (= si*gt everywhere, select-free)
//   HR = ror8(pr.y); Fv = c2? HR:pr.y; Ov = c2? pr.y:HR
// State cs = -2*log2e*c; h replicated as h[u] in all 64 lanes.
__global__ __launch_bounds__(128,1) void k2_lstm(
    const float* __restrict__ g1pre,
    const float* __restrict__ w_hh1,
    const float* __restrict__ w_ih2, const float* __restrict__ w_hh2,
    const float* __restrict__ b_ih2, const float* __restrict__ b_hh2,
    float* __restrict__ zout)
{
  __shared__ float ring[256*64];   // 64 KB exactly
  const int b = blockIdx.x;
  const int tid = threadIdx.x;
  const int wv = tid >> 6;
  const int lane = tid & 63;
  const int u = lane & 7;
  const bool c2 = (lane >> 3) & 1;
  const bool up = (lane >> 5) & 1;
  const bool isg = (c2 && !up);
  // half-form activation constants: y = A2*rcp(fma(e,.5,.5)) + D
  const float A2 = isg ? (-2.f*LOG2E) : 0.5f;
  const float D_ = isg ? ( 2.f*LOG2E) : 0.f;
  const float Sx = isg ? (-2.f*LOG2E) : (-LOG2E);

  if (wv == 0){
    // ---------------- Wave A: LSTM1 + ff for LSTM2 ----------------
    const int prow = u + (c2 ? 16 : 0) + (up ? 8 : 0);     // W1 rows i|f|g|o
    float wp[8];
    #pragma unroll
    for (int m=0;m<8;++m) wp[m] = w_hh1[prow*8 + (u^m)] * Sx;
    // LSTM2 input-projection weights for row r2 (this lane's gate/unit)
    const int r2 = u + (c2 ? 14 : 0) + (up ? 7 : 0);       // W2 rows (H2=7)
    float wff[8]; float pre2A = 0.f;
    #pragma unroll
    for (int m=0;m<8;++m) wff[m] = 0.f;
    if (u < 7){
      #pragma unroll
      for (int m=0;m<8;++m) wff[m] = w_ih2[r2*8 + (u^m)] * Sx;
      pre2A = (b_ih2[r2]+b_hh2[r2])*Sx;
    }
    const float* pA = g1pre + (size_t)b*T_*32 + prow;
    float pf[16];
    #pragma unroll
    for (int i=0;i<16;++i) pf[i] = pA[(size_t)i*32];
    float hq=0.f, csq=0.f;
    for (int c=0;c<NC;++c){
      asm volatile("s_waitcnt lgkmcnt(0)\ns_barrier" ::: "memory");
      for (int s0=0;s0<CHUNK;s0+=16){
        #pragma unroll
        for (int si=0;si<16;++si){
          const int s = s0+si;
          const int t = c*CHUNK+s;
          float pre = pf[s&15];
          int tn = t+16; if (tn>T_-1) tn=T_-1;
          pf[s&15] = pA[(size_t)tn*32];
          // gathers: all depth <= 2 (0x1B = quad reverse = xor3)
          float x1 = dppf<0xB1>(hq);
          float x2 = dppf<0x4E>(hq);
          float x3 = dppf<0x1B>(hq);
          float x4 = dppf<0x124>(hq);
          float x5 = dppf<0x124>(x1);
          float x6 = dppf<0x124>(x2);
          float x7 = dppf<0x124>(x3);
          float A0 = fmaf(wp[0], hq, pre);
          A0 = fmaf(wp[4], x4, A0);
          float p2 = wp[2]*x2;
          float p3 = wp[3]*x3;
          A0 = fmaf(wp[1], x1, A0);
          float P2 = fmaf(wp[6], x6, p2);
          float P3 = fmaf(wp[7], x7, p3);
          float p5 = wp[5]*x5;
          A0 = A0 + p5;
          float g = A0 + (P2+P3);
          float e = exp2_fast(g);
          float tg = fmaf(e, 0.5f, 0.5f);
          float r = rcp_fast(tg);
          float y = fmaf(A2, r, D_);
          v2i_t pr = __builtin_amdgcn_permlane32_swap(__float_as_int(y), __float_as_int(y), false, false);
          float lov = __int_as_float(pr.x);
          float hiv = __int_as_float(pr.y);
          float IG = lov * ror8(lov);
          float HR = ror8(hiv);
          float Fv = c2 ? HR : hiv;
          float Ov = c2 ? hiv : HR;
          float cs = fmaf(Fv, csq, IG);
          float e2 = exp2_fast(cs);
          float t2 = fmaf(e2, 0.5f, 0.5f);
          float r2v = rcp_fast(t2);
          float hn = fmaf(Ov, r2v, -Ov);       // sig(o)*tanh(c)
          csq = cs; hq = hn;
          // th = tanh(h1) and ff = W_ih2*th + bias (all off the h-chain)
          float e3 = exp2_fast(hn * (-2.f*LOG2E));
          float t3 = fmaf(e3, 0.5f, 0.5f);
          float th = rcp_fast(t3) - 1.f;
          float f1 = dppf<0xB1>(th);
          float f2 = dppf<0x4E>(th);
          float f3 = dppf<0x1B>(th);
          float f4 = dppf<0x124>(th);
          float f5 = dppf<0x124>(f1);
          float f6 = dppf<0x124>(f2);
          float f7 = dppf<0x124>(f3);
          float F0 = fmaf(wff[0], th, pre2A);
          F0 = fmaf(wff[4], f4, F0);
          float q2 = wff[2]*f2;
          float q3 = wff[3]*f3;
          F0 = fmaf(wff[1], f1, F0);
          q2 = fmaf(wff[6], f6, q2);
          q3 = fmaf(wff[7], f7, q3);
          float q5 = wff[5]*f5;
          F0 = F0 + q5;
          float ffv = F0 + (q2+q3);
          ring[((t&RMASK)<<6) + lane] = ffv;   // all 64 lanes, no exec mask
        }
      }
    }
    asm volatile("s_waitcnt lgkmcnt(0)\ns_barrier" ::: "memory");
    asm volatile("s_barrier" ::: "memory");
  } else {
    // ---------------- Wave B: LSTM2 recurrence ----------------
    const int r2 = u + (c2 ? 14 : 0) + (up ? 7 : 0);
    float wb[8];
    #pragma unroll
    for (int m=0;m<8;++m) wb[m] = 0.f;
    if (u < 7){
      #pragma unroll
      for (int m=0;m<8;++m){ int jm = u^m; wb[m] = (jm<7) ? w_hh2[r2*7+jm]*Sx : 0.f; }
    }
    float* zb = zout + (size_t)b*T_*H2_;
    float hq=0.f, csq=0.f;
    asm volatile("s_barrier" ::: "memory");   // pairs A barrier(chunk 0)
    asm volatile("s_barrier" ::: "memory");   // pairs A barrier(chunk 1): chunk 0 ready
    float fpf[8];
    #pragma unroll
    for (int i=0;i<8;++i) fpf[i] = ring[(i<<6) + lane];
    float zs[8];
    const int srow = lane >> 3;      // step-within-burst this lane stores
    for (int cb=2; cb<NC+2; ++cb){
      asm volatile("s_barrier" ::: "memory");
      const int base_t = (cb-2)*CHUNK;
      for (int s0=0;s0<CHUNK;s0+=8){
        #pragma unroll
        for (int si=0;si<8;++si){
          const int s = s0+si;
          const int t = base_t + s;
          float ffv = fpf[s&7];
          int tp = t+8; if (tp>T_-1) tp=T_-1;
          fpf[s&7] = ring[((tp&RMASK)<<6) + lane];
          float x1 = dppf<0xB1>(hq);
          float x2 = dppf<0x4E>(hq);
          float x3 = dppf<0x1B>(hq);
          float x4 = dppf<0x124>(hq);
          float x5 = dppf<0x124>(x1);
          float x6 = dppf<0x124>(x2);
          float x7 = dppf<0x124>(x3);
          float A0 = fmaf(wb[0], hq, ffv);
          A0 = fmaf(wb[4], x4, A0);
          float p2 = wb[2]*x2;
          float p3 = wb[3]*x3;
          A0 = fmaf(wb[1], x1, A0);
          float P2 = fmaf(wb[6], x6, p2);
          float P3 = fmaf(wb[7], x7, p3);
          float p5 = wb[5]*x5;
          A0 = A0 + p5;
          float g = A0 + (P2+P3);
          float e = exp2_fast(g);
          float tg = fmaf(e, 0.5f, 0.5f);
          float r = rcp_fast(tg);
          float y = fmaf(A2, r, D_);
          v2i_t pr = __builtin_amdgcn_permlane32_swap(__float_as_int(y), __float_as_int(y), false, false);
          float lov = __int_as_float(pr.x);
          float hiv = __int_as_float(pr.y);
          float IG = lov * ror8(lov);
          float HR = ror8(hiv);
          float Fv = c2 ? HR : hiv;
          float Ov = c2 ? hiv : HR;
          float cs = fmaf(Fv, csq, IG);
          float e2 = exp2_fast(cs);
          float t2 = fmaf(e2, 0.5f, 0.5f);
          float r2v = rcp_fast(t2);
          float hn = fmaf(Ov, r2v, -Ov);
          csq = cs; hq = hn;
          float e3 = exp2_fast(hn * (-2.f*LOG2E));
          float t3 = fmaf(e3, 0.5f, 0.5f);
          zs[si] = rcp_fast(t3) - 1.f;         // z = tanh(h2), replicated z[u]
        }
        // burst store: lane L -> step srow=L>>3, unit u=L&7 (u<7)
        float v0 = ((lane>>3)&1) ? zs[1] : zs[0];
        float v1 = ((lane>>3)&1) ? zs[3] : zs[2];
        float v2 = ((lane>>3)&1) ? zs[5] : zs[4];
        float v3 = ((lane>>3)&1) ? zs[7] : zs[6];
        float w0 = ((lane>>4)&1) ? v1 : v0;
        float w1 = ((lane>>4)&1) ? v3 : v2;
        float zo = ((lane>>5)&1) ? w1 : w0;
        if (u < 7) zb[(size_t)(base_t + s0 + srow)*H2_ + u] = zo;
      }
    }
  }
}

// ---------------- Kernel 3: S[b,k] = sum_t Q[b,t,k] ------------------------
__global__ __launch_bounds__(256) void k3_S(const float* __restrict__ zout,
    const float* __restrict__ centers, float* __restrict__ S)
{
  int b = blockIdx.x; int tid = threadIdx.x;
  float cc[K_]; float cw[K_][H2_];
  #pragma unroll
  for (int k=0;k<K_;++k){ float s=0.f;
    #pragma unroll
    for (int j=0;j<H2_;++j){ float c=centers[k*H2_+j]; cw[k][j]=c; s+=c*c; }
    cc[k]=s; }
  float acc[K_];
  #pragma unroll
  for (int k=0;k<K_;++k) acc[k]=0.f;
  const float* zb = zout + (size_t)b*T_*H2_;
  for (int t=tid; t<T_; t+=256){
    float zv[H2_]; float zz=0.f;
    #pragma unroll
    for (int j=0;j<H2_;++j){ zv[j]=zb[(size_t)t*H2_+j]; zz+=zv[j]*zv[j]; }
    #pragma unroll
    for (int k=0;k<K_;++k){
      float d = zz + cc[k];
      #pragma unroll
      for (int j=0;j<H2_;++j) d -= 2.f*cw[k][j]*zv[j];
      acc[k] += rcp_fast(1.f + d);
    }
  }
  __shared__ float sred[4][K_];
  int wid = tid>>6;
  #pragma unroll
  for (int k=0;k<K_;++k){
    float v = acc[k];
    #pragma unroll
    for (int off=32; off; off>>=1) v += __shfl_down(v, off);
    acc[k]=v;
  }
  if ((tid&63)==0){
    #pragma unroll
    for (int k=0;k<K_;++k) sred[wid][k]=acc[k];
  }
  __syncthreads();
  if (tid < K_){
    S[b*K_+tid] = sred[0][tid]+sred[1][tid]+sred[2][tid]+sred[3][tid];
  }
}

// ---------------- Kernel 4: decoder + fq/fp --------------------------------
__global__ __launch_bounds__(256) void k4_out(const float* __restrict__ zout,
    const float* __restrict__ dec_w, const float* __restrict__ dec_b,
    const float* __restrict__ centers, const float* __restrict__ S,
    float* __restrict__ xr, float* __restrict__ fp, float* __restrict__ fq)
{
  int idx = blockIdx.x*256 + threadIdx.x;
  if (idx >= B_*T_) return;
  int b = idx >> 13;   // /T_
  float zv[H2_]; float zz=0.f;
  const float* zp = zout + (size_t)idx*H2_;
  #pragma unroll
  for (int j=0;j<H2_;++j){ zv[j]=zp[j]; zz+=zv[j]*zv[j]; }
  float2 xo[5];
  #pragma unroll
  for (int f=0; f<F_; ++f){
    float a = dec_b[f];
    #pragma unroll
    for (int c=0;c<H2_;++c) a += zv[c]*dec_w[c*F_+f];
    (&xo[0].x)[f] = a;
  }
  float2* xp2 = (float2*)(xr + (size_t)idx*F_);
  #pragma unroll
  for (int c=0;c<5;++c) xp2[c] = xo[c];

  float Q[K_], P[K_]; float qs=0.f, ps=0.f;
  #pragma unroll
  for (int k=0;k<K_;++k){
    float d = zz;
    #pragma unroll
    for (int j=0;j<H2_;++j){ float c=centers[k*H2_+j]; d += c*c - 2.f*c*zv[j]; }
    float q = rcp_fast(1.f+d);
    Q[k]=q; qs+=q;
    float p = q*q*rcp_fast(S[b*K_+k]);
    P[k]=p; ps+=p;
  }
  float iq = rcp_fast(qs), ip = rcp_fast(ps);
  float4* fqp = (float4*)(fq + (size_t)idx*K_);
  float4* fpp = (float4*)(fp + (size_t)idx*K_);
  #pragma unroll
  for (int c=0;c<4;++c){
    float4 vq, vp;
    vq.x=Q[4*c+0]*iq; vq.y=Q[4*c+1]*iq; vq.z=Q[4*c+2]*iq; vq.w=Q[4*c+3]*iq;
    vp.x=P[4*c+0]*ip; vp.y=P[4*c+1]*ip; vp.z=P[4*c+2]*ip; vp.w=P[4*c+3]*ip;
    fqp[c]=vq; fpp[c]=vp;
  }
}

extern "C" void kernel_launch(void* const* d_in, const int* in_sizes, int n_in,
                              void* d_out, int out_size, void* d_ws, size_t ws_size,
                              hipStream_t stream)
{
  (void)in_sizes; (void)n_in; (void)out_size; (void)ws_size;
  const float* x      = (const float*)d_in[0];
  const float* conv_w = (const float*)d_in[1];
  const float* conv_b = (const float*)d_in[2];
  const float* w_ih1  = (const float*)d_in[3];
  const float* w_hh1  = (const float*)d_in[4];
  const float* b_ih1  = (const float*)d_in[5];
  const float* b_hh1  = (const float*)d_in[6];
  const float* w_ih2  = (const float*)d_in[7];
  const float* w_hh2  = (const float*)d_in[8];
  const float* b_ih2  = (const float*)d_in[9];
  const float* b_hh2  = (const float*)d_in[10];
  const float* dec_w  = (const float*)d_in[11];
  const float* dec_b  = (const float*)d_in[12];
  const float* centers= (const float*)d_in[13];

  float* out = (float*)d_out;
  float* z   = out;                              // [B,T,7]
  float* xr  = out + (size_t)B_*T_*H2_;          // [B,T,10]
  float* fp  = xr  + (size_t)B_*T_*F_;           // [B,T,16]
  float* fq  = fp  + (size_t)B_*T_*K_;           // [B,T,16]

  float* g1pre = (float*)d_ws;                   // 128 MB: [B,T,32] (pre-scaled)
  float* S     = (float*)d_ws;                   // reused after k2: [B,K]

  k1_pre<<<dim3((B_*T_)/32), dim3(256), 0, stream>>>(x, conv_w, conv_b, w_ih1, b_ih1, b_hh1, g1pre);
  k2_lstm<<<dim3(B_), dim3(128), 0, stream>>>(g1pre, w_hh1, w_ih2, w_hh2, b_ih2, b_hh2, z);
  k3_S<<<dim3(B_), dim3(256), 0, stream>>>(z, centers, S);
  k4_out<<<dim3((B_*T_)/256), dim3(256), 0, stream>>>(z, dec_w, dec_b, centers, S, xr, fp, fq);
}

// Round 7
// 1022.061 us; speedup vs baseline: 1.3134x; 1.3134x over previous
//
#include <hip/hip_runtime.h>
#include <cstdint>
#include <cstddef>

#define B_ 128
#define T_ 8192
#define F_ 10
#define F1_ 8
#define H1_ 8
#define H2_ 7
#define K_ 16
#define CHUNK 64
#define NC (T_/CHUNK)   // 128

#define LOG2E 1.4426950408889634f

__device__ __forceinline__ float exp2_fast(float x){ float r; asm("v_exp_f32 %0, %1" : "=v"(r) : "v"(x)); return r; }
__device__ __forceinline__ float rcp_fast(float x){ float r; asm("v_rcp_f32 %0, %1" : "=v"(r) : "v"(x)); return r; }
template<int CTRL>
__device__ __forceinline__ float dppf(float x){
  return __int_as_float(__builtin_amdgcn_update_dpp(0, __float_as_int(x), CTRL, 0xF, 0xF, true));
}
// xor8 within each 16-lane row (row_ror:8) -- validated r2-r6
__device__ __forceinline__ float ror8(float x){ return dppf<0x128>(x); }
typedef int v2i_t __attribute__((ext_vector_type(2)));

// ---------------- Kernel 1: precompute LSTM1 gate inputs (pre-scaled) ------
__global__ __launch_bounds__(256) void k1_pre(const float* __restrict__ x,
    const float* __restrict__ conv_w, const float* __restrict__ conv_b,
    const float* __restrict__ w_ih1, const float* __restrict__ b_ih1,
    const float* __restrict__ b_hh1, float* __restrict__ g1pre)
{
  int g8 = threadIdx.x >> 3;
  int gl = threadIdx.x & 7;
  size_t idx = (size_t)blockIdx.x*32 + g8;    // (b*T + t)
  const float* xp = x + idx*F_;
  float xv[F_];
  #pragma unroll
  for (int f=0; f<F_; ++f) xv[f] = xp[f];
  float enc[F1_];
  #pragma unroll
  for (int o=0;o<F1_;++o){
    float a = conv_b[o];
    #pragma unroll
    for (int f=0;f<F_;++f) a += conv_w[o*F_+f]*xv[f];
    enc[o] = a > 0.f ? a : 0.01f*a;   // leaky_relu 0.01
  }
  float4 out;
  #pragma unroll
  for (int q=0;q<4;++q){
    int row = gl*4+q;
    float a = b_ih1[row]+b_hh1[row];
    #pragma unroll
    for (int o=0;o<F1_;++o) a += w_ih1[row*F1_+o]*enc[o];
    float s = (row>=16 && row<24) ? (-2.f*LOG2E) : (-LOG2E);  // fold act scale
    (&out.x)[q] = a*s;
  }
  ((float4*)(g1pre + idx*32))[gl] = out;
}

// ---------------- Kernel 2: 3-wave pipelined stacked LSTMs -----------------
// Wave A: LSTM1 recurrence -> raw h1 ring.   Wave B: LSTM2 recurrence
// (ffv is the gate base) -> raw h2 ring.      Wave C (chainless): tanh(h1)
// + W_ih2 projection -> ff ring; tanh(h2) -> z global stores.
// Rings are depth-2 (even/odd chunk parity). Iteration k: A writes h1[k],
// C makes ff[k-1] and z[k-3], B makes h2[k-2]. One barrier per iteration.
// Gate lane blocks (lane>>3): [i, g, i, g | f, o, f, o]; unit u = lane&7.
// Post-activation algebra (validated r5/r6): pr = permlane32_swap(y,y);
//   IG = pr.x*ror8(pr.x); HR = ror8(pr.y); Fv = c2?HR:pr.y; Ov = c2?pr.y:HR.
// State cs = -2*log2e*c; h replicated as h[u] in all 64 lanes.
__global__ __launch_bounds__(192,1) void k2_lstm(
    const float* __restrict__ g1pre,
    const float* __restrict__ w_hh1,
    const float* __restrict__ w_ih2, const float* __restrict__ w_hh2,
    const float* __restrict__ b_ih2, const float* __restrict__ b_hh2,
    float* __restrict__ zout)
{
  __shared__ float h1r[2*CHUNK*64];   // 32 KB raw h1
  __shared__ float ffr[2*CHUNK*64];   // 32 KB ff = W_ih2*tanh(h1)+biases (scaled)
  __shared__ float h2r[2*CHUNK*64];   // 32 KB raw h2
  const int b = blockIdx.x;
  const int tid = threadIdx.x;
  const int wv = tid >> 6;
  const int lane = tid & 63;
  const int u = lane & 7;
  const bool c2 = (lane >> 3) & 1;
  const bool up = (lane >> 5) & 1;
  const bool isg = (c2 && !up);
  const float A2 = isg ? (-2.f*LOG2E) : 0.5f;
  const float D_ = isg ? ( 2.f*LOG2E) : 0.f;
  const float Sx = isg ? (-2.f*LOG2E) : (-LOG2E);

  if (wv == 0){
    // ---------------- Wave A: LSTM1 recurrence only ----------------
    const int prow = u + (c2 ? 16 : 0) + (up ? 8 : 0);     // W1 rows i|f|g|o
    float wp[8];
    #pragma unroll
    for (int m=0;m<8;++m) wp[m] = w_hh1[prow*8 + (u^m)] * Sx;
    const float* pA = g1pre + (size_t)b*T_*32 + prow;
    float pf[16];
    #pragma unroll
    for (int i=0;i<16;++i) pf[i] = pA[(size_t)i*32];
    float hq=0.f, csq=0.f;
    for (int k=0;k<NC+3;++k){
      if (k < NC){
        float* hp = &h1r[(k&1)*CHUNK*64];
        for (int s0=0;s0<CHUNK;s0+=16){
          #pragma unroll
          for (int si=0;si<16;++si){
            const int s = s0+si;
            const int t = k*CHUNK+s;
            float pre = pf[s&15];
            int tn = t+16; if (tn>T_-1) tn=T_-1;
            pf[s&15] = pA[(size_t)tn*32];
            float x1 = dppf<0xB1>(hq);
            float x2 = dppf<0x4E>(hq);
            float x3 = dppf<0x1B>(hq);
            float x4 = dppf<0x124>(hq);
            float x5 = dppf<0x124>(x1);
            float x6 = dppf<0x124>(x2);
            float x7 = dppf<0x124>(x3);
            float A0 = fmaf(wp[0], hq, pre);
            A0 = fmaf(wp[4], x4, A0);
            float p2 = wp[2]*x2;
            float p3 = wp[3]*x3;
            A0 = fmaf(wp[1], x1, A0);
            float P2 = fmaf(wp[6], x6, p2);
            float P3 = fmaf(wp[7], x7, p3);
            float p5 = wp[5]*x5;
            A0 = A0 + p5;
            float g = A0 + (P2+P3);
            float e = exp2_fast(g);
            float tg = fmaf(e, 0.5f, 0.5f);
            float r = rcp_fast(tg);
            float y = fmaf(A2, r, D_);
            v2i_t pr = __builtin_amdgcn_permlane32_swap(__float_as_int(y), __float_as_int(y), false, false);
            float lov = __int_as_float(pr.x);
            float hiv = __int_as_float(pr.y);
            float IG = lov * ror8(lov);
            float HR = ror8(hiv);
            float Fv = c2 ? HR : hiv;
            float Ov = c2 ? hiv : HR;
            float cs = fmaf(Fv, csq, IG);
            float e2 = exp2_fast(cs);
            float t2 = fmaf(e2, 0.5f, 0.5f);
            float r2v = rcp_fast(t2);
            float hn = fmaf(Ov, r2v, -Ov);
            csq = cs; hq = hn;
            hp[(s<<6) + lane] = hn;           // raw h1, all lanes
          }
        }
      }
      asm volatile("s_waitcnt lgkmcnt(0)\ns_barrier" ::: "memory");
    }
  } else if (wv == 1){
    // ---------------- Wave B: LSTM2 recurrence only ----------------
    const int r2 = u + (c2 ? 14 : 0) + (up ? 7 : 0);       // W2 rows (H2=7)
    float wb[8];
    #pragma unroll
    for (int m=0;m<8;++m) wb[m] = 0.f;
    if (u < 7){
      #pragma unroll
      for (int m=0;m<8;++m){ int jm = u^m; wb[m] = (jm<7) ? w_hh2[r2*7+jm]*Sx : 0.f; }
    }
    float hq=0.f, csq=0.f;
    for (int k=0;k<NC+3;++k){
      if (k>=2 && k<NC+2){
        const int slot = k&1;                // (k-2)&1
        const float* fp_ = &ffr[slot*CHUNK*64];
        float* hp = &h2r[slot*CHUNK*64];
        float fpf[8];
        #pragma unroll
        for (int i=0;i<8;++i) fpf[i] = fp_[(i<<6)+lane];
        for (int s0=0;s0<CHUNK;s0+=8){
          #pragma unroll
          for (int si=0;si<8;++si){
            const int s = s0+si;
            float ffv = fpf[si];
            int rp = s+8; if (rp>CHUNK-1) rp = CHUNK-1;
            fpf[si] = fp_[(rp<<6)+lane];
            float x1 = dppf<0xB1>(hq);
            float x2 = dppf<0x4E>(hq);
            float x3 = dppf<0x1B>(hq);
            float x4 = dppf<0x124>(hq);
            float x5 = dppf<0x124>(x1);
            float x6 = dppf<0x124>(x2);
            float x7 = dppf<0x124>(x3);
            float A0 = fmaf(wb[0], hq, ffv);
            A0 = fmaf(wb[4], x4, A0);
            float p2 = wb[2]*x2;
            float p3 = wb[3]*x3;
            A0 = fmaf(wb[1], x1, A0);
            float P2 = fmaf(wb[6], x6, p2);
            float P3 = fmaf(wb[7], x7, p3);
            float p5 = wb[5]*x5;
            A0 = A0 + p5;
            float g = A0 + (P2+P3);
            float e = exp2_fast(g);
            float tg = fmaf(e, 0.5f, 0.5f);
            float r = rcp_fast(tg);
            float y = fmaf(A2, r, D_);
            v2i_t pr = __builtin_amdgcn_permlane32_swap(__float_as_int(y), __float_as_int(y), false, false);
            float lov = __int_as_float(pr.x);
            float hiv = __int_as_float(pr.y);
            float IG = lov * ror8(lov);
            float HR = ror8(hiv);
            float Fv = c2 ? HR : hiv;
            float Ov = c2 ? hiv : HR;
            float cs = fmaf(Fv, csq, IG);
            float e2 = exp2_fast(cs);
            float t2 = fmaf(e2, 0.5f, 0.5f);
            float r2v = rcp_fast(t2);
            float hn = fmaf(Ov, r2v, -Ov);
            csq = cs; hq = hn;
            hp[(s<<6) + lane] = hn;           // raw h2, all lanes
          }
        }
      }
      asm volatile("s_waitcnt lgkmcnt(0)\ns_barrier" ::: "memory");
    }
  } else {
    // ---------------- Wave C: all feed-forward work ----------------
    const int r2 = u + (c2 ? 14 : 0) + (up ? 7 : 0);
    float wff[8]; float pre2A = 0.f;
    #pragma unroll
    for (int m=0;m<8;++m) wff[m] = 0.f;
    if (u < 7){
      #pragma unroll
      for (int m=0;m<8;++m) wff[m] = w_ih2[r2*8 + (u^m)] * Sx;
      pre2A = (b_ih2[r2]+b_hh2[r2])*Sx;
    }
    float* zb = zout + (size_t)b*T_*H2_;
    const int srow = lane >> 3;
    for (int k=0;k<NC+3;++k){
      if (k>=1 && k<NC+1){
        const int slot = (k-1)&1;
        const float* h1p = &h1r[slot*CHUNK*64];
        float* ffp = &ffr[slot*CHUNK*64];
        for (int s0=0;s0<CHUNK;s0+=8){
          #pragma unroll
          for (int si=0;si<8;++si){
            const int s = s0+si;
            float hv = h1p[(s<<6)+lane];
            float e3 = exp2_fast(hv * (-2.f*LOG2E));
            float t3 = fmaf(e3, 0.5f, 0.5f);
            float th = rcp_fast(t3) - 1.f;    // tanh(h1), replicated th[u]
            float f1 = dppf<0xB1>(th);
            float f2 = dppf<0x4E>(th);
            float f3 = dppf<0x1B>(th);
            float f4 = dppf<0x124>(th);
            float f5 = dppf<0x124>(f1);
            float f6 = dppf<0x124>(f2);
            float f7 = dppf<0x124>(f3);
            float F0 = fmaf(wff[0], th, pre2A);
            F0 = fmaf(wff[4], f4, F0);
            float q2 = wff[2]*f2;
            float q3 = wff[3]*f3;
            F0 = fmaf(wff[1], f1, F0);
            q2 = fmaf(wff[6], f6, q2);
            q3 = fmaf(wff[7], f7, q3);
            float q5 = wff[5]*f5;
            F0 = F0 + q5;
            float ffv = F0 + (q2+q3);
            ffp[(s<<6)+lane] = ffv;
          }
        }
      }
      if (k>=3 && k<NC+3){
        const int slot = (k-1)&1;             // (k-3)&1
        const float* h2p = &h2r[slot*CHUNK*64];
        const int base_t = (k-3)*CHUNK;
        for (int s0=0;s0<CHUNK;s0+=8){
          float zs[8];
          #pragma unroll
          for (int si=0;si<8;++si){
            float hv = h2p[((s0+si)<<6)+lane];
            float e3 = exp2_fast(hv * (-2.f*LOG2E));
            float t3 = fmaf(e3, 0.5f, 0.5f);
            zs[si] = rcp_fast(t3) - 1.f;      // z = tanh(h2), replicated z[u]
          }
          float v0 = ((lane>>3)&1) ? zs[1] : zs[0];
          float v1 = ((lane>>3)&1) ? zs[3] : zs[2];
          float v2 = ((lane>>3)&1) ? zs[5] : zs[4];
          float v3 = ((lane>>3)&1) ? zs[7] : zs[6];
          float w0 = ((lane>>4)&1) ? v1 : v0;
          float w1 = ((lane>>4)&1) ? v3 : v2;
          float zo = ((lane>>5)&1) ? w1 : w0;
          if (u < 7) zb[(size_t)(base_t + s0 + srow)*H2_ + u] = zo;
        }
      }
      asm volatile("s_waitcnt lgkmcnt(0)\ns_barrier" ::: "memory");
    }
  }
}

// ---------------- Kernel 3: S[b,k] = sum_t Q[b,t,k] ------------------------
__global__ __launch_bounds__(256) void k3_S(const float* __restrict__ zout,
    const float* __restrict__ centers, float* __restrict__ S)
{
  int b = blockIdx.x; int tid = threadIdx.x;
  float cc[K_]; float cw[K_][H2_];
  #pragma unroll
  for (int k=0;k<K_;++k){ float s=0.f;
    #pragma unroll
    for (int j=0;j<H2_;++j){ float c=centers[k*H2_+j]; cw[k][j]=c; s+=c*c; }
    cc[k]=s; }
  float acc[K_];
  #pragma unroll
  for (int k=0;k<K_;++k) acc[k]=0.f;
  const float* zb = zout + (size_t)b*T_*H2_;
  for (int t=tid; t<T_; t+=256){
    float zv[H2_]; float zz=0.f;
    #pragma unroll
    for (int j=0;j<H2_;++j){ zv[j]=zb[(size_t)t*H2_+j]; zz+=zv[j]*zv[j]; }
    #pragma unroll
    for (int k=0;k<K_;++k){
      float d = zz + cc[k];
      #pragma unroll
      for (int j=0;j<H2_;++j) d -= 2.f*cw[k][j]*zv[j];
      acc[k] += rcp_fast(1.f + d);
    }
  }
  __shared__ float sred[4][K_];
  int wid = tid>>6;
  #pragma unroll
  for (int k=0;k<K_;++k){
    float v = acc[k];
    #pragma unroll
    for (int off=32; off; off>>=1) v += __shfl_down(v, off);
    acc[k]=v;
  }
  if ((tid&63)==0){
    #pragma unroll
    for (int k=0;k<K_;++k) sred[wid][k]=acc[k];
  }
  __syncthreads();
  if (tid < K_){
    S[b*K_+tid] = sred[0][tid]+sred[1][tid]+sred[2][tid]+sred[3][tid];
  }
}

// ---------------- Kernel 4: decoder + fq/fp --------------------------------
__global__ __launch_bounds__(256) void k4_out(const float* __restrict__ zout,
    const float* __restrict__ dec_w, const float* __restrict__ dec_b,
    const float* __restrict__ centers, const float* __restrict__ S,
    float* __restrict__ xr, float* __restrict__ fp, float* __restrict__ fq)
{
  int idx = blockIdx.x*256 + threadIdx.x;
  if (idx >= B_*T_) return;
  int b = idx >> 13;   // /T_
  float zv[H2_]; float zz=0.f;
  const float* zp = zout + (size_t)idx*H2_;
  #pragma unroll
  for (int j=0;j<H2_;++j){ zv[j]=zp[j]; zz+=zv[j]*zv[j]; }
  float2 xo[5];
  #pragma unroll
  for (int f=0; f<F_; ++f){
    float a = dec_b[f];
    #pragma unroll
    for (int c=0;c<H2_;++c) a += zv[c]*dec_w[c*F_+f];
    (&xo[0].x)[f] = a;
  }
  float2* xp2 = (float2*)(xr + (size_t)idx*F_);
  #pragma unroll
  for (int c=0;c<5;++c) xp2[c] = xo[c];

  float Q[K_], P[K_]; float qs=0.f, ps=0.f;
  #pragma unroll
  for (int k=0;k<K_;++k){
    float d = zz;
    #pragma unroll
    for (int j=0;j<H2_;++j){ float c=centers[k*H2_+j]; d += c*c - 2.f*c*zv[j]; }
    float q = rcp_fast(1.f+d);
    Q[k]=q; qs+=q;
    float p = q*q*rcp_fast(S[b*K_+k]);
    P[k]=p; ps+=p;
  }
  float iq = rcp_fast(qs), ip = rcp_fast(ps);
  float4* fqp = (float4*)(fq + (size_t)idx*K_);
  float4* fpp = (float4*)(fp + (size_t)idx*K_);
  #pragma unroll
  for (int c=0;c<4;++c){
    float4 vq, vp;
    vq.x=Q[4*c+0]*iq; vq.y=Q[4*c+1]*iq; vq.z=Q[4*c+2]*iq; vq.w=Q[4*c+3]*iq;
    vp.x=P[4*c+0]*ip; vp.y=P[4*c+1]*ip; vp.z=P[4*c+2]*ip; vp.w=P[4*c+3]*ip;
    fqp[c]=vq; fpp[c]=vp;
  }
}

extern "C" void kernel_launch(void* const* d_in, const int* in_sizes, int n_in,
                              void* d_out, int out_size, void* d_ws, size_t ws_size,
                              hipStream_t stream)
{
  (void)in_sizes; (void)n_in; (void)out_size; (void)ws_size;
  const float* x      = (const float*)d_in[0];
  const float* conv_w = (const float*)d_in[1];
  const float* conv_b = (const float*)d_in[2];
  const float* w_ih1  = (const float*)d_in[3];
  const float* w_hh1  = (const float*)d_in[4];
  const float* b_ih1  = (const float*)d_in[5];
  const float* b_hh1  = (const float*)d_in[6];
  const float* w_ih2  = (const float*)d_in[7];
  const float* w_hh2  = (const float*)d_in[8];
  const float* b_ih2  = (const float*)d_in[9];
  const float* b_hh2  = (const float*)d_in[10];
  const float* dec_w  = (const float*)d_in[11];
  const float* dec_b  = (const float*)d_in[12];
  const float* centers= (const float*)d_in[13];

  float* out = (float*)d_out;
  float* z   = out;                              // [B,T,7]
  float* xr  = out + (size_t)B_*T_*H2_;          // [B,T,10]
  float* fp  = xr  + (size_t)B_*T_*F_;           // [B,T,16]
  float* fq  = fp  + (size_t)B_*T_*K_;           // [B,T,16]

  float* g1pre = (float*)d_ws;                   // 128 MB: [B,T,32] (pre-scaled)
  float* S     = (float*)d_ws;                   // reused after k2: [B,K]

  k1_pre<<<dim3((B_*T_)/32), dim3(256), 0, stream>>>(x, conv_w, conv_b, w_ih1, b_ih1, b_hh1, g1pre);
  k2_lstm<<<dim3(B_), dim3(192), 0, stream>>>(g1pre, w_hh1, w_ih2, w_hh2, b_ih2, b_hh2, z);
  k3_S<<<dim3(B_), dim3(256), 0, stream>>>(z, centers, S);
  k4_out<<<dim3((B_*T_)/256), dim3(256), 0, stream>>>(z, dec_w, dec_b, centers, S, xr, fp, fq);
}